// Round 8
// baseline (717.534 us; speedup 1.0000x reference)
//
#include <hip/hip_runtime.h>

#define NN 50000
#define NE 800000
#define NL 3

typedef __bf16 bf16x8 __attribute__((ext_vector_type(8)));
typedef float f32x16 __attribute__((ext_vector_type(16)));
typedef unsigned int u32x4 __attribute__((ext_vector_type(4)));

// ---------------- zero degree array ----------------
__global__ __launch_bounds__(256) void k_zero(float* __restrict__ deg) {
  int i = blockIdx.x * 256 + threadIdx.x;
  if (i < NN) deg[i] = 0.f;
}

// ---------------- degree histogram ----------------
__global__ __launch_bounds__(256) void k_deg(const int* __restrict__ trg,
                                             float* __restrict__ deg) {
  int e = blockIdx.x * 256 + threadIdx.x;
  if (e < NE) atomicAdd(&deg[trg[e]], 1.0f);
}

// ---------------- exclusive scan of degrees -> CSR row starts ----------------
__global__ __launch_bounds__(1024) void k_scan(const float* __restrict__ deg,
                                               int* __restrict__ rowstart,
                                               int* __restrict__ cursor) {
  __shared__ int part[1024];
  int t = threadIdx.x;
  int t0 = t * 49, t1 = min(t0 + 49, NN);
  int s = 0;
  for (int i = t0; i < t1; i++) s += (int)deg[i];
  part[t] = s;
  __syncthreads();
  for (int off = 1; off < 1024; off <<= 1) {
    int vv = (t >= off) ? part[t - off] : 0;
    int v = part[t];
    __syncthreads();
    part[t] = v + vv;
    __syncthreads();
  }
  int run = part[t] - s;  // exclusive prefix
  for (int i = t0; i < t1; i++) {
    rowstart[i] = run;
    cursor[i] = run;
    run += (int)deg[i];
  }
  if (t == 1023) rowstart[NN] = NE;
}

// ---------------- CSR fill: bucket src ids by trg ----------------
__global__ __launch_bounds__(256) void k_fill(const int* __restrict__ src,
                                              const int* __restrict__ trg,
                                              int* __restrict__ cursor,
                                              int* __restrict__ csr) {
  int e = blockIdx.x * 256 + threadIdx.x;
  if (e < NE) {
    int pos = atomicAdd(&cursor[trg[e]], 1);
    csr[pos] = src[e];
  }
}

__device__ inline u32x4 pack8(const float* f) {
  u32x4 r;
  #pragma unroll
  for (int i = 0; i < 4; i++) {
    unsigned short lo = __builtin_bit_cast(unsigned short, (__bf16)f[2 * i]);
    unsigned short hi = __builtin_bit_cast(unsigned short, (__bf16)f[2 * i + 1]);
    r[i] = (unsigned)lo | ((unsigned)hi << 16);
  }
  return r;
}

__device__ inline float bflo(unsigned u) {
  return __builtin_bit_cast(float, u << 16);
}
__device__ inline float bfhi(unsigned u) {
  return __builtin_bit_cast(float, u & 0xffff0000u);
}

// ---------------- bf16 mirror of x_in (layer-0 gather source) ----------------
__global__ __launch_bounds__(256) void k_xmir(const float* __restrict__ x,
                                              unsigned short* __restrict__ xb) {
  int i = blockIdx.x * 256 + threadIdx.x;   // NN*8 items, 8 elems each
  if (i < NN * 8) {
    const float4* x4 = (const float4*)x;
    float4 a = x4[2 * i], b = x4[2 * i + 1];
    float f[8] = {a.x, a.y, a.z, a.w, b.x, b.y, b.z, b.w};
    ((u32x4*)xb)[i] = pack8(f);
  }
}

// ---------------- gather aggregation v3: depth-2 x-prefetch (R7 win: kept) ----------------
__global__ __launch_bounds__(256) void k_agg(const unsigned short* __restrict__ xb,
                                             const int* __restrict__ rowstart,
                                             const int* __restrict__ csr,
                                             float* __restrict__ agg, int relu) {
  int i = blockIdx.x * 256 + threadIdx.x;
  if (i >= NN * 8) return;
  int n = i >> 3, q = i & 7;                 // chunk q: bf16 cols [8q, 8q+8)
  const u32x4* xq = (const u32x4*)xb;
  int b = rowstart[n], en = rowstart[n + 1];
  int nj = en - b;
  float acc[8] = {0.f, 0.f, 0.f, 0.f, 0.f, 0.f, 0.f, 0.f};
  u32x4 v0 = {}, v1 = {};
  if (nj > 0) v0 = xq[(size_t)csr[b] * 8 + q];
  if (nj > 1) v1 = xq[(size_t)csr[b + 1] * 8 + q];
  for (int j = 0; j < nj; j++) {
    u32x4 v = v0;
    v0 = v1;
    if (j + 2 < nj) v1 = xq[(size_t)csr[b + j + 2] * 8 + q];
    #pragma unroll
    for (int c = 0; c < 4; c++) {
      float lo = bflo(v[c]), hi = bfhi(v[c]);
      if (relu) { lo = fmaxf(lo, 0.f); hi = fmaxf(hi, 0.f); }
      acc[2 * c] += lo;
      acc[2 * c + 1] += hi;
    }
  }
  float inv = 1.0f / fmaxf((float)nj, 1.0f);
  float4 o0 = {acc[0] * inv, acc[1] * inv, acc[2] * inv, acc[3] * inv};
  float4 o1 = {acc[4] * inv, acc[5] * inv, acc[6] * inv, acc[7] * inv};
  float4* a4 = (float4*)agg;
  a4[(size_t)n * 16 + q * 2] = o0;
  a4[(size_t)n * 16 + q * 2 + 1] = o1;
}

// ---------------- node conv: xout = relu?(x)@Ws + agg@Wn + b (+ bf16 mirror) ----------------
__global__ __launch_bounds__(256) void k_conv(const float* __restrict__ x,
                                              const float* __restrict__ agg,
                                              const float* __restrict__ Ws,
                                              const float* __restrict__ Wn,
                                              const float* __restrict__ bc,
                                              float* __restrict__ xout,
                                              unsigned short* __restrict__ xb,
                                              int relu) {
  __shared__ float sWs[64 * 64];
  __shared__ float sWn[64 * 64];
  __shared__ float sx[4][64];
  __shared__ float sa[4][64];
  int tid = threadIdx.x;
  for (int i = tid; i < 4096; i += 256) { sWs[i] = Ws[i]; sWn[i] = Wn[i]; }
  int g = tid >> 6, lane = tid & 63;
  int n = blockIdx.x * 4 + g;
  float xv = x[(size_t)n * 64 + lane];
  if (relu) xv = fmaxf(xv, 0.f);
  sx[g][lane] = xv;
  sa[g][lane] = agg[(size_t)n * 64 + lane];
  __syncthreads();
  float acc = bc[lane];
  #pragma unroll
  for (int k = 0; k < 64; k++) {
    acc += sx[g][k] * sWs[k * 64 + lane] + sa[g][k] * sWn[k * 64 + lane];
  }
  xout[(size_t)n * 64 + lane] = acc;
  xb[(size_t)n * 64 + lane] = __builtin_bit_cast(unsigned short, (__bf16)acc);
}

// ---------------- W_fc prep into MFMA-B LDS layout ----------------
// Wt2[l][ks][kg][col][e] = bf16(W_fc[l][ks*16+kg*8+e][col]); 32KB per layer.
__global__ __launch_bounds__(256) void k_wprep(const float* __restrict__ Wfc,
                                               unsigned short* __restrict__ Wt) {
  int idx = blockIdx.x * 256 + threadIdx.x;   // [0, 3*16384)
  int l = idx >> 14;
  int o = idx & 16383;
  int e = o & 7;
  int col = (o >> 3) & 63;
  int kg = (o >> 9) & 1;
  int ks = o >> 10;
  int k = ks * 16 + kg * 8 + e;
  float v = Wfc[((size_t)l * 257 + k) * 64 + col];
  Wt[idx] = __builtin_bit_cast(unsigned short, (__bf16)v);
}

// ---------------- edge update v8 (reverted from v9): one tile/wave, Wt in LDS ----------------
// R7 post-mortem: the 5-tile/wave pipeline (v9) traded TLP (occ 37->18%) for
// ILP and LOST (116 -> 130us). The wave scheduler already overlaps
// independent waves' gathers; keep one tile/wave at launch_bounds(256,4),
// 6250 blocks, 52 VGPR -- the empirically fastest form (R4/R6: ~116us).
template <int IN_BF16, int OUT_BF16>
__global__ __launch_bounds__(256, 4) void k_edge(
    const unsigned short* __restrict__ xb, const int* __restrict__ src,
    const int* __restrict__ trg, const void* ef_in,
    const unsigned short* __restrict__ Wt, const float* __restrict__ w256,
    const float* __restrict__ bfc, void* ef_out) {
  __shared__ __align__(16) unsigned short sB[16384];  // 32KB: [ks][kg][col][8]

  int t = threadIdx.x;
  // ---- stage Wt -> LDS (linear, coalesced, L2-hot) ----
  {
    const u32x4* wg = (const u32x4*)Wt;
    u32x4* sb = (u32x4*)sB;
    #pragma unroll
    for (int i = 0; i < 8; i++) sb[t + 256 * i] = wg[t + 256 * i];
  }
  __syncthreads();
  const u32x4* sb4 = (const u32x4*)sB;

  int w = t >> 6;
  int lane = t & 63;
  int rl = lane & 31;   // edge within tile == MFMA row == output col offset
  int kg = lane >> 5;   // k-half
  int e0 = (blockIdx.x * 4 + w) * 32;
  int e = e0 + rl;

  int se = src[e], te = trg[e];

  // ---- issue ef load first (streaming) ----
  u32x4 efr[4];
  if (IN_BF16) {
    const u32x4* eb = (const u32x4*)ef_in;
    #pragma unroll
    for (int j = 0; j < 4; j++) efr[j] = eb[(size_t)e * 8 + j * 2 + kg];
  } else {
    const float4* ef4 = (const float4*)ef_in;
    #pragma unroll
    for (int j = 0; j < 4; j++) {
      float4 a = ef4[(size_t)e * 16 + j * 4 + kg * 2];
      float4 b = ef4[(size_t)e * 16 + j * 4 + kg * 2 + 1];
      float f[8] = {a.x, a.y, a.z, a.w, b.x, b.y, b.z, b.w};
      efr[j] = pack8(f);
    }
  }

  // ---- issue x gathers (random bf16 128B rows) ----
  const u32x4* xq = (const u32x4*)xb;
  u32x4 sfr[4], tfr[4];
  #pragma unroll
  for (int j = 0; j < 4; j++) {
    sfr[j] = xq[(size_t)se * 8 + j * 2 + kg];
    tfr[j] = xq[(size_t)te * 8 + j * 2 + kg];
  }

  int col0 = rl, col1 = 32 + rl;
  float wv0 = w256[col0], wv1 = w256[col1];
  f32x16 acc0, acc1;
  {
    float b0 = bfc[col0], b1 = bfc[col1];
    #pragma unroll
    for (int r = 0; r < 16; r++) { acc0[r] = b0; acc1[r] = b1; }
  }

  // ---- ef MFMAs (k 0..63): overlap x-gather latency ----
  #pragma unroll
  for (int ks = 0; ks < 4; ks++) {
    bf16x8 av = __builtin_bit_cast(bf16x8, efr[ks]);
    int bi = (ks * 2 + kg) * 64;
    acc0 = __builtin_amdgcn_mfma_f32_32x32x16_bf16(
        av, __builtin_bit_cast(bf16x8, sb4[bi + col0]), acc0, 0, 0, 0);
    acc1 = __builtin_amdgcn_mfma_f32_32x32x16_bf16(
        av, __builtin_bit_cast(bf16x8, sb4[bi + col1]), acc1, 0, 0, 0);
  }
  // ---- xs MFMAs (k 64..127) ----
  #pragma unroll
  for (int ks = 4; ks < 8; ks++) {
    bf16x8 av = __builtin_bit_cast(bf16x8, sfr[ks - 4]);
    int bi = (ks * 2 + kg) * 64;
    acc0 = __builtin_amdgcn_mfma_f32_32x32x16_bf16(
        av, __builtin_bit_cast(bf16x8, sb4[bi + col0]), acc0, 0, 0, 0);
    acc1 = __builtin_amdgcn_mfma_f32_32x32x16_bf16(
        av, __builtin_bit_cast(bf16x8, sb4[bi + col1]), acc1, 0, 0, 0);
  }
  // ---- xt MFMAs (k 128..191) ----
  #pragma unroll
  for (int ks = 8; ks < 12; ks++) {
    bf16x8 av = __builtin_bit_cast(bf16x8, tfr[ks - 8]);
    int bi = (ks * 2 + kg) * 64;
    acc0 = __builtin_amdgcn_mfma_f32_32x32x16_bf16(
        av, __builtin_bit_cast(bf16x8, sb4[bi + col0]), acc0, 0, 0, 0);
    acc1 = __builtin_amdgcn_mfma_f32_32x32x16_bf16(
        av, __builtin_bit_cast(bf16x8, sb4[bi + col1]), acc1, 0, 0, 0);
  }

  // ---- sim partials + |xs-xt| frags (from bf16-rounded values) ----
  float dot = 0.f, n1 = 0.f, n2 = 0.f;
  u32x4 dfr[4];
  #pragma unroll
  for (int j = 0; j < 4; j++) {
    float fs[8], ft[8], fd[8];
    #pragma unroll
    for (int q = 0; q < 4; q++) {
      fs[2 * q] = bflo(sfr[j][q]); fs[2 * q + 1] = bfhi(sfr[j][q]);
      ft[2 * q] = bflo(tfr[j][q]); ft[2 * q + 1] = bfhi(tfr[j][q]);
    }
    #pragma unroll
    for (int c = 0; c < 8; c++) {
      dot = fmaf(fs[c], ft[c], dot);
      n1 = fmaf(fs[c], fs[c], n1);
      n2 = fmaf(ft[c], ft[c], n2);
      fd[c] = fabsf(fs[c] - ft[c]);
    }
    dfr[j] = pack8(fd);
  }

  // ---- |xs-xt| MFMAs (k 192..255) ----
  #pragma unroll
  for (int ks = 12; ks < 16; ks++) {
    bf16x8 av = __builtin_bit_cast(bf16x8, dfr[ks - 12]);
    int bi = (ks * 2 + kg) * 64;
    acc0 = __builtin_amdgcn_mfma_f32_32x32x16_bf16(
        av, __builtin_bit_cast(bf16x8, sb4[bi + col0]), acc0, 0, 0, 0);
    acc1 = __builtin_amdgcn_mfma_f32_32x32x16_bf16(
        av, __builtin_bit_cast(bf16x8, sb4[bi + col1]), acc1, 0, 0, 0);
  }

  // ---- combine kg-halves -> sim; fold sim-column (k=256) into output ----
  dot += __shfl_xor(dot, 32);
  n1 += __shfl_xor(n1, 32);
  n2 += __shfl_xor(n2, 32);
  float sim = dot / fmaxf(sqrtf(n1) * sqrtf(n2), 1e-8f);

  // ---- store C (bf16 inter-layer, fp32 final) ----
  #pragma unroll
  for (int r = 0; r < 16; r++) {
    int row = (r & 3) + 8 * (r >> 2) + 4 * kg;
    float s = __shfl(sim, row);
    float o0 = fmaf(s, wv0, acc0[r]);
    float o1 = fmaf(s, wv1, acc1[r]);
    size_t base = (size_t)(e0 + row) * 64;
    if (OUT_BF16) {
      unsigned short* ob = (unsigned short*)ef_out;
      ob[base + col0] = __builtin_bit_cast(unsigned short, (__bf16)o0);
      ob[base + col1] = __builtin_bit_cast(unsigned short, (__bf16)o1);
    } else {
      float* of = (float*)ef_out;
      of[base + col0] = o0;
      of[base + col1] = o1;
    }
  }
}

extern "C" void kernel_launch(void* const* d_in, const int* in_sizes, int n_in,
                              void* d_out, int out_size, void* d_ws, size_t ws_size,
                              hipStream_t stream) {
  const float* x_in   = (const float*)d_in[0];
  const int*   ei     = (const int*)d_in[1];
  const float* ef_in  = (const float*)d_in[2];
  const float* W_self = (const float*)d_in[3];
  const float* W_nbr  = (const float*)d_in[4];
  const float* b_conv = (const float*)d_in[5];
  const float* W_fc   = (const float*)d_in[6];
  const float* b_fc   = (const float*)d_in[7];
  float* out = (float*)d_out;

  const int* src = ei;
  const int* trg = ei + NE;

  char* ws = (char*)d_ws;
  size_t off = 0;
  float* deg      = (float*)(ws + off); off += (((size_t)NN * 4) + 255) & ~(size_t)255;
  int*   rowstart = (int*)(ws + off);   off += (((size_t)(NN + 1) * 4) + 255) & ~(size_t)255;
  int*   cursor   = (int*)(ws + off);   off += (((size_t)NN * 4) + 255) & ~(size_t)255;
  int*   csr      = (int*)(ws + off);   off += (size_t)NE * 4;
  float* agg      = (float*)(ws + off); off += (size_t)NN * 64 * 4;
  float* x_a      = (float*)(ws + off); off += (size_t)NN * 64 * 4;
  float* x_b      = (float*)(ws + off); off += (size_t)NN * 64 * 4;
  unsigned short* Wt  = (unsigned short*)(ws + off); off += (size_t)NL * 16384 * 2;
  unsigned short* efb = (unsigned short*)(ws + off); off += (size_t)NE * 64 * 2;
  unsigned short* xbm = (unsigned short*)(ws + off); off += (size_t)NN * 64 * 2;

  k_zero<<<(NN + 255) / 256, 256, 0, stream>>>(deg);
  k_deg<<<(NE + 255) / 256, 256, 0, stream>>>(trg, deg);
  k_scan<<<1, 1024, 0, stream>>>(deg, rowstart, cursor);
  k_fill<<<(NE + 255) / 256, 256, 0, stream>>>(src, trg, cursor, csr);
  k_wprep<<<(NL * 16384) / 256, 256, 0, stream>>>(W_fc, Wt);
  k_xmir<<<(NN * 8 + 255) / 256, 256, 0, stream>>>(x_in, xbm);

  const float* xcur = x_in;
  float* xnext = x_a;

  for (int i = 0; i < NL; i++) {
    int relu = (i > 0) ? 1 : 0;
    k_agg<<<(NN * 8 + 255) / 256, 256, 0, stream>>>(xbm, rowstart, csr, agg, relu);
    k_conv<<<NN / 4, 256, 0, stream>>>(xcur, agg,
                                       W_self + (size_t)i * 4096,
                                       W_nbr + (size_t)i * 4096,
                                       b_conv + (size_t)i * 64,
                                       xnext, xbm, relu);
    const unsigned short* Wti = Wt + (size_t)i * 16384;
    const float* w256 = W_fc + ((size_t)i * 257 + 256) * 64;
    const float* bfc = b_fc + (size_t)i * 64;
    if (i == 0) {
      k_edge<0, 1><<<NE / 128, 256, 0, stream>>>(xbm, src, trg, ef_in,
                                                 Wti, w256, bfc, efb);
    } else if (i == 1) {
      k_edge<1, 1><<<NE / 128, 256, 0, stream>>>(xbm, src, trg, efb,
                                                 Wti, w256, bfc, efb);
    } else {
      k_edge<1, 0><<<NE / 128, 256, 0, stream>>>(xbm, src, trg, efb,
                                                 Wti, w256, bfc, out);
    }
    xcur = xnext;
    xnext = (xnext == x_a) ? x_b : x_a;
  }
}

// Round 9
// 701.526 us; speedup vs baseline: 1.0228x; 1.0228x over previous
//
#include <hip/hip_runtime.h>

#define NN 50000
#define NE 800000
#define NL 3

typedef __bf16 bf16x8 __attribute__((ext_vector_type(8)));
typedef float f32x16 __attribute__((ext_vector_type(16)));
typedef unsigned int u32x4 __attribute__((ext_vector_type(4)));

// ---------------- zero degree array ----------------
__global__ __launch_bounds__(256) void k_zero(float* __restrict__ deg) {
  int i = blockIdx.x * 256 + threadIdx.x;
  if (i < NN) deg[i] = 0.f;
}

// ---------------- degree histogram ----------------
__global__ __launch_bounds__(256) void k_deg(const int* __restrict__ trg,
                                             float* __restrict__ deg) {
  int e = blockIdx.x * 256 + threadIdx.x;
  if (e < NE) atomicAdd(&deg[trg[e]], 1.0f);
}

// ---------------- exclusive scan of degrees -> CSR row starts ----------------
__global__ __launch_bounds__(1024) void k_scan(const float* __restrict__ deg,
                                               int* __restrict__ rowstart,
                                               int* __restrict__ cursor) {
  __shared__ int part[1024];
  int t = threadIdx.x;
  int t0 = t * 49, t1 = min(t0 + 49, NN);
  int s = 0;
  for (int i = t0; i < t1; i++) s += (int)deg[i];
  part[t] = s;
  __syncthreads();
  for (int off = 1; off < 1024; off <<= 1) {
    int vv = (t >= off) ? part[t - off] : 0;
    int v = part[t];
    __syncthreads();
    part[t] = v + vv;
    __syncthreads();
  }
  int run = part[t] - s;  // exclusive prefix
  for (int i = t0; i < t1; i++) {
    rowstart[i] = run;
    cursor[i] = run;
    run += (int)deg[i];
  }
  if (t == 1023) rowstart[NN] = NE;
}

// ---------------- CSR fill: bucket by trg; also emit edge-id + trg per position ----------------
// Position space p (trg-sorted) is the k_edge processing order: srcp = csr,
// trgp[p] = trg, eid[p] = original edge id (for layer-0 ef gather + final
// scatter store). Within-run order is atomic-nondeterministic but harmless:
// everything is indexed through eid.
__global__ __launch_bounds__(256) void k_fill(const int* __restrict__ src,
                                              const int* __restrict__ trg,
                                              int* __restrict__ cursor,
                                              int* __restrict__ csr,
                                              int* __restrict__ eid,
                                              int* __restrict__ trgp) {
  int e = blockIdx.x * 256 + threadIdx.x;
  if (e < NE) {
    int tv = trg[e];
    int pos = atomicAdd(&cursor[tv], 1);
    csr[pos] = src[e];
    eid[pos] = e;
    trgp[pos] = tv;
  }
}

__device__ inline u32x4 pack8(const float* f) {
  u32x4 r;
  #pragma unroll
  for (int i = 0; i < 4; i++) {
    unsigned short lo = __builtin_bit_cast(unsigned short, (__bf16)f[2 * i]);
    unsigned short hi = __builtin_bit_cast(unsigned short, (__bf16)f[2 * i + 1]);
    r[i] = (unsigned)lo | ((unsigned)hi << 16);
  }
  return r;
}

__device__ inline float bflo(unsigned u) {
  return __builtin_bit_cast(float, u << 16);
}
__device__ inline float bfhi(unsigned u) {
  return __builtin_bit_cast(float, u & 0xffff0000u);
}

// ---------------- bf16 mirror of x_in (layer-0 gather source) ----------------
__global__ __launch_bounds__(256) void k_xmir(const float* __restrict__ x,
                                              unsigned short* __restrict__ xb) {
  int i = blockIdx.x * 256 + threadIdx.x;   // NN*8 items, 8 elems each
  if (i < NN * 8) {
    const float4* x4 = (const float4*)x;
    float4 a = x4[2 * i], b = x4[2 * i + 1];
    float f[8] = {a.x, a.y, a.z, a.w, b.x, b.y, b.z, b.w};
    ((u32x4*)xb)[i] = pack8(f);
  }
}

// ---------------- gather aggregation v3: depth-2 x-prefetch ----------------
__global__ __launch_bounds__(256) void k_agg(const unsigned short* __restrict__ xb,
                                             const int* __restrict__ rowstart,
                                             const int* __restrict__ csr,
                                             float* __restrict__ agg, int relu) {
  int i = blockIdx.x * 256 + threadIdx.x;
  if (i >= NN * 8) return;
  int n = i >> 3, q = i & 7;                 // chunk q: bf16 cols [8q, 8q+8)
  const u32x4* xq = (const u32x4*)xb;
  int b = rowstart[n], en = rowstart[n + 1];
  int nj = en - b;
  float acc[8] = {0.f, 0.f, 0.f, 0.f, 0.f, 0.f, 0.f, 0.f};
  u32x4 v0 = {}, v1 = {};
  if (nj > 0) v0 = xq[(size_t)csr[b] * 8 + q];
  if (nj > 1) v1 = xq[(size_t)csr[b + 1] * 8 + q];
  for (int j = 0; j < nj; j++) {
    u32x4 v = v0;
    v0 = v1;
    if (j + 2 < nj) v1 = xq[(size_t)csr[b + j + 2] * 8 + q];
    #pragma unroll
    for (int c = 0; c < 4; c++) {
      float lo = bflo(v[c]), hi = bfhi(v[c]);
      if (relu) { lo = fmaxf(lo, 0.f); hi = fmaxf(hi, 0.f); }
      acc[2 * c] += lo;
      acc[2 * c + 1] += hi;
    }
  }
  float inv = 1.0f / fmaxf((float)nj, 1.0f);
  float4 o0 = {acc[0] * inv, acc[1] * inv, acc[2] * inv, acc[3] * inv};
  float4 o1 = {acc[4] * inv, acc[5] * inv, acc[6] * inv, acc[7] * inv};
  float4* a4 = (float4*)agg;
  a4[(size_t)n * 16 + q * 2] = o0;
  a4[(size_t)n * 16 + q * 2 + 1] = o1;
}

// ---------------- node conv: xout = relu?(x)@Ws + agg@Wn + b (+ bf16 mirror) ----------------
__global__ __launch_bounds__(256) void k_conv(const float* __restrict__ x,
                                              const float* __restrict__ agg,
                                              const float* __restrict__ Ws,
                                              const float* __restrict__ Wn,
                                              const float* __restrict__ bc,
                                              float* __restrict__ xout,
                                              unsigned short* __restrict__ xb,
                                              int relu) {
  __shared__ float sWs[64 * 64];
  __shared__ float sWn[64 * 64];
  __shared__ float sx[4][64];
  __shared__ float sa[4][64];
  int tid = threadIdx.x;
  for (int i = tid; i < 4096; i += 256) { sWs[i] = Ws[i]; sWn[i] = Wn[i]; }
  int g = tid >> 6, lane = tid & 63;
  int n = blockIdx.x * 4 + g;
  float xv = x[(size_t)n * 64 + lane];
  if (relu) xv = fmaxf(xv, 0.f);
  sx[g][lane] = xv;
  sa[g][lane] = agg[(size_t)n * 64 + lane];
  __syncthreads();
  float acc = bc[lane];
  #pragma unroll
  for (int k = 0; k < 64; k++) {
    acc += sx[g][k] * sWs[k * 64 + lane] + sa[g][k] * sWn[k * 64 + lane];
  }
  xout[(size_t)n * 64 + lane] = acc;
  xb[(size_t)n * 64 + lane] = __builtin_bit_cast(unsigned short, (__bf16)acc);
}

// ---------------- W_fc prep into MFMA-B LDS layout ----------------
// Wt2[l][ks][kg][col][e] = bf16(W_fc[l][ks*16+kg*8+e][col]); 32KB per layer.
__global__ __launch_bounds__(256) void k_wprep(const float* __restrict__ Wfc,
                                               unsigned short* __restrict__ Wt) {
  int idx = blockIdx.x * 256 + threadIdx.x;   // [0, 3*16384)
  int l = idx >> 14;
  int o = idx & 16383;
  int e = o & 7;
  int col = (o >> 3) & 63;
  int kg = (o >> 9) & 1;
  int ks = o >> 10;
  int k = ks * 16 + kg * 8 + e;
  float v = Wfc[((size_t)l * 257 + k) * 64 + col];
  Wt[idx] = __builtin_bit_cast(unsigned short, (__bf16)v);
}

// ---------------- edge update v10: trg-sorted permuted processing ----------------
// Request accounting (v8): x-gathers 256 + ef 128 + stores 64 ~ 450 req/wave,
// ~97K req/us -> still request/latency bound. Processing edges in trg-sorted
// position space makes each 32-edge tile share ~2-3 te nodes: the 4 te-gather
// instrs coalesce 128 -> ~12 requests and te rows go L1-hot. se stays random
// (irreducible). efb lives in permuted space (linear, pattern unchanged);
// layer-0 ef gathered via eid (same 32 segs/instr as before); final store
// scatters to out[eid] (same 2 segs/instr). Per-edge math bit-identical.
template <int IN_BF16, int OUT_BF16>
__global__ __launch_bounds__(256, 4) void k_edge(
    const unsigned short* __restrict__ xb, const int* __restrict__ srcp,
    const int* __restrict__ trgp, const int* __restrict__ eid,
    const void* ef_in, const unsigned short* __restrict__ Wt,
    const float* __restrict__ w256, const float* __restrict__ bfc,
    void* ef_out) {
  __shared__ __align__(16) unsigned short sB[16384];  // 32KB: [ks][kg][col][8]

  int t = threadIdx.x;
  // ---- stage Wt -> LDS (linear, coalesced, L2-hot) ----
  {
    const u32x4* wg = (const u32x4*)Wt;
    u32x4* sb = (u32x4*)sB;
    #pragma unroll
    for (int i = 0; i < 8; i++) sb[t + 256 * i] = wg[t + 256 * i];
  }
  __syncthreads();
  const u32x4* sb4 = (const u32x4*)sB;

  int w = t >> 6;
  int lane = t & 63;
  int rl = lane & 31;   // position within tile == MFMA row == output col offset
  int kg = lane >> 5;   // k-half
  int e0 = (blockIdx.x * 4 + w) * 32;
  int e = e0 + rl;      // permuted position

  int se = srcp[e], te = trgp[e];
  int eidv = eid[e];    // original edge id

  // ---- issue ef load first ----
  u32x4 efr[4];
  if (IN_BF16) {
    // efb is in permuted space: linear rows
    const u32x4* eb = (const u32x4*)ef_in;
    #pragma unroll
    for (int j = 0; j < 4; j++) efr[j] = eb[(size_t)e * 8 + j * 2 + kg];
  } else {
    // layer 0: gather original ef rows by edge id
    const float4* ef4 = (const float4*)ef_in;
    #pragma unroll
    for (int j = 0; j < 4; j++) {
      float4 a = ef4[(size_t)eidv * 16 + j * 4 + kg * 2];
      float4 b = ef4[(size_t)eidv * 16 + j * 4 + kg * 2 + 1];
      float f[8] = {a.x, a.y, a.z, a.w, b.x, b.y, b.z, b.w};
      efr[j] = pack8(f);
    }
  }

  // ---- x gathers: te near-broadcast (sorted), se random ----
  const u32x4* xq = (const u32x4*)xb;
  u32x4 sfr[4], tfr[4];
  #pragma unroll
  for (int j = 0; j < 4; j++) {
    sfr[j] = xq[(size_t)se * 8 + j * 2 + kg];
    tfr[j] = xq[(size_t)te * 8 + j * 2 + kg];
  }

  int col0 = rl, col1 = 32 + rl;
  float wv0 = w256[col0], wv1 = w256[col1];
  f32x16 acc0, acc1;
  {
    float b0 = bfc[col0], b1 = bfc[col1];
    #pragma unroll
    for (int r = 0; r < 16; r++) { acc0[r] = b0; acc1[r] = b1; }
  }

  // ---- ef MFMAs (k 0..63) ----
  #pragma unroll
  for (int ks = 0; ks < 4; ks++) {
    bf16x8 av = __builtin_bit_cast(bf16x8, efr[ks]);
    int bi = (ks * 2 + kg) * 64;
    acc0 = __builtin_amdgcn_mfma_f32_32x32x16_bf16(
        av, __builtin_bit_cast(bf16x8, sb4[bi + col0]), acc0, 0, 0, 0);
    acc1 = __builtin_amdgcn_mfma_f32_32x32x16_bf16(
        av, __builtin_bit_cast(bf16x8, sb4[bi + col1]), acc1, 0, 0, 0);
  }
  // ---- xs MFMAs (k 64..127) ----
  #pragma unroll
  for (int ks = 4; ks < 8; ks++) {
    bf16x8 av = __builtin_bit_cast(bf16x8, sfr[ks - 4]);
    int bi = (ks * 2 + kg) * 64;
    acc0 = __builtin_amdgcn_mfma_f32_32x32x16_bf16(
        av, __builtin_bit_cast(bf16x8, sb4[bi + col0]), acc0, 0, 0, 0);
    acc1 = __builtin_amdgcn_mfma_f32_32x32x16_bf16(
        av, __builtin_bit_cast(bf16x8, sb4[bi + col1]), acc1, 0, 0, 0);
  }
  // ---- xt MFMAs (k 128..191) ----
  #pragma unroll
  for (int ks = 8; ks < 12; ks++) {
    bf16x8 av = __builtin_bit_cast(bf16x8, tfr[ks - 8]);
    int bi = (ks * 2 + kg) * 64;
    acc0 = __builtin_amdgcn_mfma_f32_32x32x16_bf16(
        av, __builtin_bit_cast(bf16x8, sb4[bi + col0]), acc0, 0, 0, 0);
    acc1 = __builtin_amdgcn_mfma_f32_32x32x16_bf16(
        av, __builtin_bit_cast(bf16x8, sb4[bi + col1]), acc1, 0, 0, 0);
  }

  // ---- sim partials + |xs-xt| frags (from bf16-rounded values) ----
  float dot = 0.f, n1 = 0.f, n2 = 0.f;
  u32x4 dfr[4];
  #pragma unroll
  for (int j = 0; j < 4; j++) {
    float fs[8], ft[8], fd[8];
    #pragma unroll
    for (int q = 0; q < 4; q++) {
      fs[2 * q] = bflo(sfr[j][q]); fs[2 * q + 1] = bfhi(sfr[j][q]);
      ft[2 * q] = bflo(tfr[j][q]); ft[2 * q + 1] = bfhi(tfr[j][q]);
    }
    #pragma unroll
    for (int c = 0; c < 8; c++) {
      dot = fmaf(fs[c], ft[c], dot);
      n1 = fmaf(fs[c], fs[c], n1);
      n2 = fmaf(ft[c], ft[c], n2);
      fd[c] = fabsf(fs[c] - ft[c]);
    }
    dfr[j] = pack8(fd);
  }

  // ---- |xs-xt| MFMAs (k 192..255) ----
  #pragma unroll
  for (int ks = 12; ks < 16; ks++) {
    bf16x8 av = __builtin_bit_cast(bf16x8, dfr[ks - 12]);
    int bi = (ks * 2 + kg) * 64;
    acc0 = __builtin_amdgcn_mfma_f32_32x32x16_bf16(
        av, __builtin_bit_cast(bf16x8, sb4[bi + col0]), acc0, 0, 0, 0);
    acc1 = __builtin_amdgcn_mfma_f32_32x32x16_bf16(
        av, __builtin_bit_cast(bf16x8, sb4[bi + col1]), acc1, 0, 0, 0);
  }

  // ---- combine kg-halves -> sim; fold sim-column (k=256) into output ----
  dot += __shfl_xor(dot, 32);
  n1 += __shfl_xor(n1, 32);
  n2 += __shfl_xor(n2, 32);
  float sim = dot / fmaxf(sqrtf(n1) * sqrtf(n2), 1e-8f);

  // ---- store C: bf16 to permuted efb (linear), fp32 final scatter via eid ----
  #pragma unroll
  for (int r = 0; r < 16; r++) {
    int row = (r & 3) + 8 * (r >> 2) + 4 * kg;
    float s = __shfl(sim, row);
    float o0 = fmaf(s, wv0, acc0[r]);
    float o1 = fmaf(s, wv1, acc1[r]);
    if (OUT_BF16) {
      size_t base = (size_t)(e0 + row) * 64;
      unsigned short* ob = (unsigned short*)ef_out;
      ob[base + col0] = __builtin_bit_cast(unsigned short, (__bf16)o0);
      ob[base + col1] = __builtin_bit_cast(unsigned short, (__bf16)o1);
    } else {
      int er = __shfl(eidv, row);  // lane 'row' holds eid[e0+row]
      size_t base = (size_t)er * 64;
      float* of = (float*)ef_out;
      of[base + col0] = o0;
      of[base + col1] = o1;
    }
  }
}

extern "C" void kernel_launch(void* const* d_in, const int* in_sizes, int n_in,
                              void* d_out, int out_size, void* d_ws, size_t ws_size,
                              hipStream_t stream) {
  const float* x_in   = (const float*)d_in[0];
  const int*   ei     = (const int*)d_in[1];
  const float* ef_in  = (const float*)d_in[2];
  const float* W_self = (const float*)d_in[3];
  const float* W_nbr  = (const float*)d_in[4];
  const float* b_conv = (const float*)d_in[5];
  const float* W_fc   = (const float*)d_in[6];
  const float* b_fc   = (const float*)d_in[7];
  float* out = (float*)d_out;

  const int* src = ei;
  const int* trg = ei + NE;

  char* ws = (char*)d_ws;
  size_t off = 0;
  float* deg      = (float*)(ws + off); off += (((size_t)NN * 4) + 255) & ~(size_t)255;
  int*   rowstart = (int*)(ws + off);   off += (((size_t)(NN + 1) * 4) + 255) & ~(size_t)255;
  int*   cursor   = (int*)(ws + off);   off += (((size_t)NN * 4) + 255) & ~(size_t)255;
  int*   csr      = (int*)(ws + off);   off += (size_t)NE * 4;
  int*   eid      = (int*)(ws + off);   off += (size_t)NE * 4;
  int*   trgp     = (int*)(ws + off);   off += (size_t)NE * 4;
  float* agg      = (float*)(ws + off); off += (size_t)NN * 64 * 4;
  float* x_a      = (float*)(ws + off); off += (size_t)NN * 64 * 4;
  float* x_b      = (float*)(ws + off); off += (size_t)NN * 64 * 4;
  unsigned short* Wt  = (unsigned short*)(ws + off); off += (size_t)NL * 16384 * 2;
  unsigned short* efb = (unsigned short*)(ws + off); off += (size_t)NE * 64 * 2;
  unsigned short* xbm = (unsigned short*)(ws + off); off += (size_t)NN * 64 * 2;

  k_zero<<<(NN + 255) / 256, 256, 0, stream>>>(deg);
  k_deg<<<(NE + 255) / 256, 256, 0, stream>>>(trg, deg);
  k_scan<<<1, 1024, 0, stream>>>(deg, rowstart, cursor);
  k_fill<<<(NE + 255) / 256, 256, 0, stream>>>(src, trg, cursor, csr, eid, trgp);
  k_wprep<<<(NL * 16384) / 256, 256, 0, stream>>>(W_fc, Wt);
  k_xmir<<<(NN * 8 + 255) / 256, 256, 0, stream>>>(x_in, xbm);

  const float* xcur = x_in;
  float* xnext = x_a;

  for (int i = 0; i < NL; i++) {
    int relu = (i > 0) ? 1 : 0;
    k_agg<<<(NN * 8 + 255) / 256, 256, 0, stream>>>(xbm, rowstart, csr, agg, relu);
    k_conv<<<NN / 4, 256, 0, stream>>>(xcur, agg,
                                       W_self + (size_t)i * 4096,
                                       W_nbr + (size_t)i * 4096,
                                       b_conv + (size_t)i * 64,
                                       xnext, xbm, relu);
    const unsigned short* Wti = Wt + (size_t)i * 16384;
    const float* w256 = W_fc + ((size_t)i * 257 + 256) * 64;
    const float* bfc = b_fc + (size_t)i * 64;
    if (i == 0) {
      k_edge<0, 1><<<NE / 128, 256, 0, stream>>>(xbm, csr, trgp, eid, ef_in,
                                                 Wti, w256, bfc, efb);
    } else if (i == 1) {
      k_edge<1, 1><<<NE / 128, 256, 0, stream>>>(xbm, csr, trgp, eid, efb,
                                                 Wti, w256, bfc, efb);
    } else {
      k_edge<1, 0><<<NE / 128, 256, 0, stream>>>(xbm, csr, trgp, eid, efb,
                                                 Wti, w256, bfc, out);
    }
    xcur = xnext;
    xnext = (xnext == x_a) ? x_b : x_a;
  }
}